// Round 12
// baseline (1892.350 us; speedup 1.0000x reference)
//
#include <hip/hip_runtime.h>
#include <hip/hip_bf16.h>

typedef __bf16 bf16x8 __attribute__((ext_vector_type(8)));
typedef float  f32x4  __attribute__((ext_vector_type(4)));
typedef unsigned long long ull;
typedef ull ull2 __attribute__((ext_vector_type(2)));

#define Bq 64
#define Sq 512
#define Iq 512
#define Hq 1024
#define TSTEPS 511
#define MB 16          // batches per group (4 groups x 32 blocks = 128 CUs)
#define NCOLS 32       // h-columns per block
#define SHq (Sq*Hq)
#define TAGM 0x0001000100010001ull

__device__ inline unsigned short f2bf(float f){ return __builtin_bit_cast(unsigned short, (__bf16)f); }

// swizzled LDS byte address for Ax (break the 1024B row-stride bank conflict)
__device__ inline unsigned ax_addr(unsigned row, unsigned k){ return ((row<<10) + (k<<1)) ^ ((row&7)<<4); }

__device__ inline bf16x8 load_wfrag(const float* p){
  float4 a = *(const float4*)p;
  float4 b = *(const float4*)(p+4);
  bf16x8 w;
  w[0]=(__bf16)a.x; w[1]=(__bf16)a.y; w[2]=(__bf16)a.z; w[3]=(__bf16)a.w;
  w[4]=(__bf16)b.x; w[5]=(__bf16)b.y; w[6]=(__bf16)b.z; w[7]=(__bf16)b.w;
  return w;
}

// anti-remat tie (keeps weight frags resident in the unified VGPR/AGPR file)
#define KEEP(v_) asm volatile("" : "+v"(v_))

// Tag protocol (r5): h^s lives in buffer s&1; every stored bf16's LSB =
// (s>>1)&1. kernel_launch memsets both buffers to 0xFF (stale for t=0/1;
// erases replay leftovers and the 0xAA ws-poison). Tag-in-data makes ANY
// read granularity safe (each bf16 individually stale or fresh).
//
// r12 change (single mechanism): h path = PER-CHUNK poll DIRECTLY into MFMA
// A-fragments. One h-kstep (32 cols) = one producer block's slice; a wave's
// A-frag for kstep j is 16B/lane at h[row=l15][w*128+j*32+l4*8]. Poll loads
// ARE the A-frags: chunk j waits on ONE producer; chunks processed in order
// so early chunks' MFMAs overlap later waits. Ah LDS deleted entirely.
// Everything else frozen at r11 (x staging coalesced->LDS, per-wave P slots,
// contiguous reduce reads, hold-in-register, 2 barriers/step, no fp LDS
// atomics).
__global__ __launch_bounds__(512, 1) void gru_kernel(
    const float* __restrict__ x, const float* __restrict__ h0,
    const float* __restrict__ w_ir, const float* __restrict__ w_iz, const float* __restrict__ w_in_,
    const float* __restrict__ b_ir, const float* __restrict__ b_iz, const float* __restrict__ b_in_,
    const float* __restrict__ w_hr, const float* __restrict__ w_hz, const float* __restrict__ w_hn,
    const float* __restrict__ b_hr, const float* __restrict__ b_hz, const float* __restrict__ b_hn,
    float* __restrict__ out, void* ws)
{
  __shared__ unsigned short Ax[MB*Iq];   // 16 KB, swizzled, wave-sliced by k-stripe
  __shared__ float P[8*2048];            // 64 KB per-wave partial slots (8 KB/wave)
  __shared__ float biasR[NCOLS], biasZ[NCOLS], biasNX[NCOLS], biasNH[NCOLS];

  const unsigned tid    = threadIdx.x;
  const unsigned bid    = blockIdx.x;
  const unsigned g      = bid & 3;        // batch group: 32 blocks
  const unsigned colbase= (bid >> 2) * NCOLS;
  const unsigned lane   = tid & 63;
  const unsigned w      = tid >> 6;       // wave = K-eighth
  const unsigned l15    = lane & 15;
  const unsigned l4     = lane >> 4;

  unsigned short* hb0 = (unsigned short*)ws;          // ping-pong tagged h buffers
  unsigned short* hb1 = hb0 + Bq*Hq;

  if (tid < NCOLS) {
    unsigned c = colbase + tid;
    biasR[tid]  = b_ir[c] + b_hr[c];
    biasZ[tid]  = b_iz[c] + b_hz[c];
    biasNX[tid] = b_in_[c];
    biasNH[tid] = b_hn[c];
  }

  // ---- reduce role: permuted 1:1 (row,col) ownership so reduce reads are
  //      CONTIGUOUS (offset = gate*512 + tid); hold lives in a REGISTER.
  const unsigned ctr = tid >> 8, Lr = (tid >> 2) & 63, ir = tid & 3;
  const unsigned rrow = ((Lr >> 4) << 2) + ir;          // 0..15
  const unsigned rcol = ctr*16 + (Lr & 15);             // 0..31
  float hold;
  {
    unsigned b = g*MB + rrow, hcol = colbase + rcol;
    hold = h0[(size_t)b*Hq + hcol];
    out[(size_t)b*SHq + hcol] = hold;
    unsigned short u = (unsigned short)(f2bf(hold) & ~1u);   // tag 0
    __hip_atomic_store(hb0 + (size_t)b*Hq + hcol, u,
                       __ATOMIC_RELAXED, __HIP_MEMORY_SCOPE_AGENT);
  }

  // ---- stationary weights: 36 frags/wave (144 regs, VGPR/AGPR unified) ----
  // B-frag (16x16x32): col = lane&15, k = (lane>>4)*8 + [0..7]
  bf16x8 wRX[2][2], wZX[2][2], wNX[2][2];   // [ct][j], x ksteps w*2+j
  bf16x8 wRH[2][4], wZH[2][4], wNH[2][4];   // [ct][j], h ksteps w*4+j
  #pragma unroll
  for (int ct = 0; ct < 2; ++ct) {
    const unsigned hcf = colbase + ct*16 + l15;
    #pragma unroll
    for (int j = 0; j < 2; ++j) {
      unsigned off = (w*2 + j)*32 + l4*8;
      wRX[ct][j] = load_wfrag(w_ir  + (size_t)hcf*Iq + off);
      wZX[ct][j] = load_wfrag(w_iz  + (size_t)hcf*Iq + off);
      wNX[ct][j] = load_wfrag(w_in_ + (size_t)hcf*Iq + off);
      KEEP(wRX[ct][j]); KEEP(wZX[ct][j]); KEEP(wNX[ct][j]);
    }
    #pragma unroll
    for (int j = 0; j < 4; ++j) {
      unsigned off = (w*4 + j)*32 + l4*8;
      wRH[ct][j] = load_wfrag(w_hr + (size_t)hcf*Hq + off);
      wZH[ct][j] = load_wfrag(w_hz + (size_t)hcf*Hq + off);
      wNH[ct][j] = load_wfrag(w_hn + (size_t)hcf*Hq + off);
      KEEP(wRH[ct][j]); KEEP(wZH[ct][j]); KEEP(wNH[ct][j]);
    }
  }

  // ---- staging roles ----
  const unsigned xcr = lane >> 4, xc16 = lane & 15;  // x: coalesced 256B row-chunks

  // ---- x prefetch for t=0 (slab 1): wave-private k-stripe, coalesced ----
  float4 xpf[4];
  #pragma unroll
  for (int i = 0; i < 4; ++i)
    xpf[i] = *(const float4*)(x + ((size_t)(g*MB + xcr + 4*i)*Sq + 1)*Iq + w*64 + xc16*4);

  for (int t = 0; t < TSTEPS; ++t) {
    const unsigned short* hs = (t & 1) ? hb1 : hb0;
    unsigned short*       hd = (t & 1) ? hb0 : hb1;
    const ull want = ((t >> 1) & 1) ? TAGM : 0ull;
    const unsigned tagd = ((t + 1) >> 1) & 1;

    // ---- stage own x stripe from prefetched regs (wave-private, no barrier) ----
    #pragma unroll
    for (int i = 0; i < 4; ++i) {
      float4 v = xpf[i];
      ull pv = (ull)f2bf(v.x) | ((ull)f2bf(v.y) << 16)
             | ((ull)f2bf(v.z) << 32) | ((ull)f2bf(v.w) << 48);
      *(ull*)((char*)Ax + ax_addr(xcr + 4*i, w*64 + xc16*4)) = pv;
    }

    // ---- issue ALL h chunk loads (per-lane A-frag addresses, 2x8B each) ----
    ull hv[4][2];
    const ull* hrow = (const ull*)(hs + (size_t)(g*MB + l15)*Hq + w*128 + l4*8);
    // chunk j at +j*32 bf16 = +j*8 ull from lane base
    #pragma unroll
    for (int j = 0; j < 4; ++j) {
      hv[j][0] = __hip_atomic_load(hrow + j*8,     __ATOMIC_RELAXED, __HIP_MEMORY_SCOPE_AGENT);
      hv[j][1] = __hip_atomic_load(hrow + j*8 + 1, __ATOMIC_RELAXED, __HIP_MEMORY_SCOPE_AGENT);
    }

    // ---- x prefetch for t+2 (hidden under poll+MFMA+reduce) ----
    {
      int tt = (t + 2 <= Sq - 1) ? (t + 2) : (Sq - 1);
      #pragma unroll
      for (int i = 0; i < 4; ++i)
        xpf[i] = *(const float4*)(x + ((size_t)(g*MB + xcr + 4*i)*Sq + (size_t)tt)*Iq + w*64 + xc16*4);
    }

    // ---- x-part MFMAs (12): run while h chunk loads are in flight ----
    f32x4 accR[2]={{0,0,0,0},{0,0,0,0}}, accZ[2]={{0,0,0,0},{0,0,0,0}};
    f32x4 accNX[2]={{0,0,0,0},{0,0,0,0}}, accNH[2]={{0,0,0,0},{0,0,0,0}};
    #pragma unroll
    for (int j = 0; j < 2; ++j) {
      bf16x8 a = *(const bf16x8*)((char*)Ax + ax_addr(l15, (w*2 + j)*32 + l4*8));
      #pragma unroll
      for (int ct = 0; ct < 2; ++ct) {
        accR[ct]  = __builtin_amdgcn_mfma_f32_16x16x32_bf16(a, wRX[ct][j], accR[ct], 0, 0, 0);
        accZ[ct]  = __builtin_amdgcn_mfma_f32_16x16x32_bf16(a, wZX[ct][j], accZ[ct], 0, 0, 0);
        accNX[ct] = __builtin_amdgcn_mfma_f32_16x16x32_bf16(a, wNX[ct][j], accNX[ct], 0, 0, 0);
      }
    }

    // ---- per-chunk: wait for chunk j (ONE producer) then 6 MFMAs ----
    #pragma unroll
    for (int j = 0; j < 4; ++j) {
      for (;;) {
        int ok = ((hv[j][0] & TAGM) == want) && ((hv[j][1] & TAGM) == want);
        if (__all(ok)) break;
        __builtin_amdgcn_s_sleep(1);
        if ((hv[j][0] & TAGM) != want)
          hv[j][0] = __hip_atomic_load(hrow + j*8,     __ATOMIC_RELAXED, __HIP_MEMORY_SCOPE_AGENT);
        if ((hv[j][1] & TAGM) != want)
          hv[j][1] = __hip_atomic_load(hrow + j*8 + 1, __ATOMIC_RELAXED, __HIP_MEMORY_SCOPE_AGENT);
      }
      ull2 hp; hp[0] = hv[j][0]; hp[1] = hv[j][1];
      bf16x8 a = __builtin_bit_cast(bf16x8, hp);   // tagged bf16 (1 ulp) feeds MFMA directly
      #pragma unroll
      for (int ct = 0; ct < 2; ++ct) {
        accR[ct]  = __builtin_amdgcn_mfma_f32_16x16x32_bf16(a, wRH[ct][j], accR[ct], 0, 0, 0);
        accZ[ct]  = __builtin_amdgcn_mfma_f32_16x16x32_bf16(a, wZH[ct][j], accZ[ct], 0, 0, 0);
        accNH[ct] = __builtin_amdgcn_mfma_f32_16x16x32_bf16(a, wNH[ct][j], accNH[ct], 0, 0, 0);
      }
    }

    // ---- per-wave partial slots: coalesced ds_write_b128 (conflict-free) ----
    {
      float* pw = P + w*2048 + lane*4;
      #pragma unroll
      for (int ct = 0; ct < 2; ++ct) {
        *(f32x4*)(pw +    0 + ct*256) = accR[ct];
        *(f32x4*)(pw +  512 + ct*256) = accZ[ct];
        *(f32x4*)(pw + 1024 + ct*256) = accNX[ct];
        *(f32x4*)(pw + 1536 + ct*256) = accNH[ct];
      }
    }
    __syncthreads();   // S3: partials visible

    // ---- reduce over 8 wave-slots (contiguous reads) + gates + stores ----
    {
      float pr = 0.f, pz = 0.f, pnx = 0.f, pnh = 0.f;
      #pragma unroll
      for (int ww = 0; ww < 8; ++ww) {
        const float* pb = P + ww*2048;
        pr  += pb[tid];
        pz  += pb[512  + tid];
        pnx += pb[1024 + tid];
        pnh += pb[1536 + tid];
      }

      float r = 1.f/(1.f + __expf(-(pr + biasR[rcol])));
      float z = 1.f/(1.f + __expf(-(pz + biasZ[rcol])));
      float nin = pnx + biasNX[rcol] + r*(pnh + biasNH[rcol]);
      float e2 = __expf(2.f*nin);
      float n = 1.f - 2.f/(e2 + 1.f);             // tanh
      float hn = (1.f - z)*n + z*hold;
      hold = hn;

      const unsigned b = g*MB + rrow, hcol = colbase + rcol;
      unsigned short u = (unsigned short)((f2bf(hn) & ~1u) | tagd);
      __hip_atomic_store(hd + (size_t)b*Hq + hcol, u,
                         __ATOMIC_RELAXED, __HIP_MEMORY_SCOPE_AGENT);
      out[(size_t)b*SHq + (size_t)(t+1)*Hq + hcol] = hn;
      if (t == TSTEPS-1)
        out[(size_t)Bq*SHq + (size_t)b*Hq + hcol] = hn;
    }
    __syncthreads();   // S4: P reads done before next step's P writes
  }
}

extern "C" void kernel_launch(void* const* d_in, const int* in_sizes, int n_in,
                              void* d_out, int out_size, void* d_ws, size_t ws_size,
                              hipStream_t stream) {
  const float* x     = (const float*)d_in[0];
  const float* h0    = (const float*)d_in[1];
  const float* w_ir  = (const float*)d_in[2];
  const float* w_iz  = (const float*)d_in[3];
  const float* w_in_ = (const float*)d_in[4];
  const float* b_ir  = (const float*)d_in[5];
  const float* b_iz  = (const float*)d_in[6];
  const float* b_in_ = (const float*)d_in[7];
  const float* w_hr  = (const float*)d_in[8];
  const float* w_hz  = (const float*)d_in[9];
  const float* w_hn  = (const float*)d_in[10];
  const float* b_hr  = (const float*)d_in[11];
  const float* b_hz  = (const float*)d_in[12];
  const float* b_hn  = (const float*)d_in[13];
  float* out = (float*)d_out;

  // Precondition both tagged h ping-pong buffers to ALL-STALE (0xFFFF: tag 1,
  // bf16 NaN) -- erases replay leftovers and the harness's 0xAA ws-poison.
  hipMemsetAsync(d_ws, 0xFF, (size_t)2 * Bq * Hq * sizeof(unsigned short), stream);

  void* args[] = { (void*)&x, (void*)&h0, (void*)&w_ir, (void*)&w_iz, (void*)&w_in_,
                   (void*)&b_ir, (void*)&b_iz, (void*)&b_in_, (void*)&w_hr, (void*)&w_hz,
                   (void*)&w_hn, (void*)&b_hr, (void*)&b_hz, (void*)&b_hn,
                   (void*)&out, (void*)&d_ws };
  hipLaunchCooperativeKernel((void*)gru_kernel, dim3(128), dim3(512), args, 0, stream);
}

// Round 13
// 1678.398 us; speedup vs baseline: 1.1275x; 1.1275x over previous
//
#include <hip/hip_runtime.h>
#include <hip/hip_bf16.h>

typedef __bf16 bf16x8 __attribute__((ext_vector_type(8)));
typedef float  f32x4  __attribute__((ext_vector_type(4)));
typedef unsigned long long ull;
typedef ull ull2 __attribute__((ext_vector_type(2)));

#define Bq 64
#define Sq 512
#define Iq 512
#define Hq 1024
#define TSTEPS 511
#define MB 16          // batches per group (4 groups x 32 blocks = 128 CUs)
#define NCOLS 32       // h-columns per block
#define SHq (Sq*Hq)
#define TAGM 0x0001000100010001ull

__device__ inline unsigned short f2bf(float f){ return __builtin_bit_cast(unsigned short, (__bf16)f); }

// swizzled LDS byte address for Ax (break the 1024B row-stride bank conflict)
__device__ inline unsigned ax_addr(unsigned row, unsigned k){ return ((row<<10) + (k<<1)) ^ ((row&7)<<4); }

__device__ inline bf16x8 load_wfrag(const float* p){
  float4 a = *(const float4*)p;
  float4 b = *(const float4*)(p+4);
  bf16x8 w;
  w[0]=(__bf16)a.x; w[1]=(__bf16)a.y; w[2]=(__bf16)a.z; w[3]=(__bf16)a.w;
  w[4]=(__bf16)b.x; w[5]=(__bf16)b.y; w[6]=(__bf16)b.z; w[7]=(__bf16)b.w;
  return w;
}

// anti-remat tie (keeps weight frags resident in the unified VGPR/AGPR file)
#define KEEP(v_) asm volatile("" : "+v"(v_))

// Tag protocol (r5): h^s lives in buffer s&1; every stored bf16's LSB =
// (s>>1)&1. kernel_launch memsets both buffers to 0xFF (stale for t=0/1;
// erases replay leftovers and the 0xAA ws-poison). Tag-in-data makes any
// read granularity safe.
//
// r13 = r12's direct-frag h path (poll loads ARE the MFMA A-frags; no Ah
// LDS) with r11's schedule hygiene restored (r12's two defects):
//   - ONE whole-stripe poll loop (r12's 4 sequential per-chunk loops each
//     paid their own sleep+L3-RTT quantum);
//   - x HBM prefetch issued AFTER poll success (r12 issued it before the
//     tag checks -> the loop's conservative vmcnt(0) put a ~900cy HBM wait
//     on the serial chain every step);
//   - the 12 x-part MFMAs moved BEFORE the poll (LDS/lgkm only -> free
//     overlap with the h-load flight).
// Freed LDS spent on parity-double-buffered P (128 KB) -> S4 deleted,
// 1 barrier/step (step-t reads of parity p finish before S3(t+1); step-t+2
// writes to p happen after it -- barrier transitivity).
__global__ __launch_bounds__(512, 1) void gru_kernel(
    const float* __restrict__ x, const float* __restrict__ h0,
    const float* __restrict__ w_ir, const float* __restrict__ w_iz, const float* __restrict__ w_in_,
    const float* __restrict__ b_ir, const float* __restrict__ b_iz, const float* __restrict__ b_in_,
    const float* __restrict__ w_hr, const float* __restrict__ w_hz, const float* __restrict__ w_hn,
    const float* __restrict__ b_hr, const float* __restrict__ b_hz, const float* __restrict__ b_hn,
    float* __restrict__ out, void* ws)
{
  __shared__ unsigned short Ax[MB*Iq];   // 16 KB, swizzled, wave-sliced by k-stripe
  __shared__ float P[2][8][2048];        // 128 KB parity-double-buffered per-wave slots
  __shared__ float biasR[NCOLS], biasZ[NCOLS], biasNX[NCOLS], biasNH[NCOLS];

  const unsigned tid    = threadIdx.x;
  const unsigned bid    = blockIdx.x;
  const unsigned g      = bid & 3;        // batch group: 32 blocks
  const unsigned colbase= (bid >> 2) * NCOLS;
  const unsigned lane   = tid & 63;
  const unsigned w      = tid >> 6;       // wave = K-eighth
  const unsigned l15    = lane & 15;
  const unsigned l4     = lane >> 4;

  unsigned short* hb0 = (unsigned short*)ws;          // ping-pong tagged h buffers
  unsigned short* hb1 = hb0 + Bq*Hq;

  if (tid < NCOLS) {
    unsigned c = colbase + tid;
    biasR[tid]  = b_ir[c] + b_hr[c];
    biasZ[tid]  = b_iz[c] + b_hz[c];
    biasNX[tid] = b_in_[c];
    biasNH[tid] = b_hn[c];
  }

  // ---- reduce role: permuted 1:1 (row,col) ownership so reduce reads are
  //      CONTIGUOUS (offset = gate*512 + tid); hold lives in a REGISTER.
  const unsigned ctr = tid >> 8, Lr = (tid >> 2) & 63, ir = tid & 3;
  const unsigned rrow = ((Lr >> 4) << 2) + ir;          // 0..15
  const unsigned rcol = ctr*16 + (Lr & 15);             // 0..31
  float hold;
  {
    unsigned b = g*MB + rrow, hcol = colbase + rcol;
    hold = h0[(size_t)b*Hq + hcol];
    out[(size_t)b*SHq + hcol] = hold;
    unsigned short u = (unsigned short)(f2bf(hold) & ~1u);   // tag 0
    __hip_atomic_store(hb0 + (size_t)b*Hq + hcol, u,
                       __ATOMIC_RELAXED, __HIP_MEMORY_SCOPE_AGENT);
  }

  // ---- stationary weights: 36 frags/wave (144 regs, VGPR/AGPR unified) ----
  // B-frag (16x16x32): col = lane&15, k = (lane>>4)*8 + [0..7]
  bf16x8 wRX[2][2], wZX[2][2], wNX[2][2];   // [ct][j], x ksteps w*2+j
  bf16x8 wRH[2][4], wZH[2][4], wNH[2][4];   // [ct][j], h ksteps w*4+j
  #pragma unroll
  for (int ct = 0; ct < 2; ++ct) {
    const unsigned hcf = colbase + ct*16 + l15;
    #pragma unroll
    for (int j = 0; j < 2; ++j) {
      unsigned off = (w*2 + j)*32 + l4*8;
      wRX[ct][j] = load_wfrag(w_ir  + (size_t)hcf*Iq + off);
      wZX[ct][j] = load_wfrag(w_iz  + (size_t)hcf*Iq + off);
      wNX[ct][j] = load_wfrag(w_in_ + (size_t)hcf*Iq + off);
      KEEP(wRX[ct][j]); KEEP(wZX[ct][j]); KEEP(wNX[ct][j]);
    }
    #pragma unroll
    for (int j = 0; j < 4; ++j) {
      unsigned off = (w*4 + j)*32 + l4*8;
      wRH[ct][j] = load_wfrag(w_hr + (size_t)hcf*Hq + off);
      wZH[ct][j] = load_wfrag(w_hz + (size_t)hcf*Hq + off);
      wNH[ct][j] = load_wfrag(w_hn + (size_t)hcf*Hq + off);
      KEEP(wRH[ct][j]); KEEP(wZH[ct][j]); KEEP(wNH[ct][j]);
    }
  }

  // ---- staging roles ----
  const unsigned xcr = lane >> 4, xc16 = lane & 15;  // x: coalesced 256B row-chunks

  // ---- x prefetch for t=0 (slab 1): wave-private k-stripe, coalesced ----
  float4 xpf[4];
  #pragma unroll
  for (int i = 0; i < 4; ++i)
    xpf[i] = *(const float4*)(x + ((size_t)(g*MB + xcr + 4*i)*Sq + 1)*Iq + w*64 + xc16*4);

  for (int t = 0; t < TSTEPS; ++t) {
    const unsigned short* hs = (t & 1) ? hb1 : hb0;
    unsigned short*       hd = (t & 1) ? hb0 : hb1;
    const ull want = ((t >> 1) & 1) ? TAGM : 0ull;
    const unsigned tagd = ((t + 1) >> 1) & 1;
    float* pcur = &P[t & 1][0][0];

    // ---- stage own x stripe from prefetched regs (wave-private, no barrier) ----
    #pragma unroll
    for (int i = 0; i < 4; ++i) {
      float4 v = xpf[i];
      ull pv = (ull)f2bf(v.x) | ((ull)f2bf(v.y) << 16)
             | ((ull)f2bf(v.z) << 32) | ((ull)f2bf(v.w) << 48);
      *(ull*)((char*)Ax + ax_addr(xcr + 4*i, w*64 + xc16*4)) = pv;
    }

    // ---- issue ALL h A-frag loads (per-lane addresses; loads ARE the frags) ----
    ull hv[4][2];
    const ull* hrow = (const ull*)(hs + (size_t)(g*MB + l15)*Hq + w*128 + l4*8);
    #pragma unroll
    for (int j = 0; j < 4; ++j) {
      hv[j][0] = __hip_atomic_load(hrow + j*8,     __ATOMIC_RELAXED, __HIP_MEMORY_SCOPE_AGENT);
      hv[j][1] = __hip_atomic_load(hrow + j*8 + 1, __ATOMIC_RELAXED, __HIP_MEMORY_SCOPE_AGENT);
    }

    // ---- x-part MFMAs (12): LDS/lgkm only -> overlap the h-load flight ----
    f32x4 accR[2]={{0,0,0,0},{0,0,0,0}}, accZ[2]={{0,0,0,0},{0,0,0,0}};
    f32x4 accNX[2]={{0,0,0,0},{0,0,0,0}}, accNH[2]={{0,0,0,0},{0,0,0,0}};
    #pragma unroll
    for (int j = 0; j < 2; ++j) {
      bf16x8 a = *(const bf16x8*)((char*)Ax + ax_addr(l15, (w*2 + j)*32 + l4*8));
      #pragma unroll
      for (int ct = 0; ct < 2; ++ct) {
        accR[ct]  = __builtin_amdgcn_mfma_f32_16x16x32_bf16(a, wRX[ct][j], accR[ct], 0, 0, 0);
        accZ[ct]  = __builtin_amdgcn_mfma_f32_16x16x32_bf16(a, wZX[ct][j], accZ[ct], 0, 0, 0);
        accNX[ct] = __builtin_amdgcn_mfma_f32_16x16x32_bf16(a, wNX[ct][j], accNX[ct], 0, 0, 0);
      }
    }

    // ---- ONE whole-stripe poll: retry only stale halves, single quantum ----
    for (;;) {
      int ok = 1;
      #pragma unroll
      for (int j = 0; j < 4; ++j)
        ok &= ((hv[j][0] & TAGM) == want) && ((hv[j][1] & TAGM) == want);
      if (__all(ok)) break;
      __builtin_amdgcn_s_sleep(1);
      #pragma unroll
      for (int j = 0; j < 4; ++j) {
        if ((hv[j][0] & TAGM) != want)
          hv[j][0] = __hip_atomic_load(hrow + j*8,     __ATOMIC_RELAXED, __HIP_MEMORY_SCOPE_AGENT);
        if ((hv[j][1] & TAGM) != want)
          hv[j][1] = __hip_atomic_load(hrow + j*8 + 1, __ATOMIC_RELAXED, __HIP_MEMORY_SCOPE_AGENT);
      }
    }

    // ---- x prefetch for t+2: AFTER poll success (off the serial chain) ----
    {
      int tt = (t + 2 <= Sq - 1) ? (t + 2) : (Sq - 1);
      #pragma unroll
      for (int i = 0; i < 4; ++i)
        xpf[i] = *(const float4*)(x + ((size_t)(g*MB + xcr + 4*i)*Sq + (size_t)tt)*Iq + w*64 + xc16*4);
    }

    // ---- h-part MFMAs (24): polled values feed MFMA directly ----
    #pragma unroll
    for (int j = 0; j < 4; ++j) {
      ull2 hp; hp[0] = hv[j][0]; hp[1] = hv[j][1];
      bf16x8 a = __builtin_bit_cast(bf16x8, hp);   // tagged bf16 (1 ulp)
      #pragma unroll
      for (int ct = 0; ct < 2; ++ct) {
        accR[ct]  = __builtin_amdgcn_mfma_f32_16x16x32_bf16(a, wRH[ct][j], accR[ct], 0, 0, 0);
        accZ[ct]  = __builtin_amdgcn_mfma_f32_16x16x32_bf16(a, wZH[ct][j], accZ[ct], 0, 0, 0);
        accNH[ct] = __builtin_amdgcn_mfma_f32_16x16x32_bf16(a, wNH[ct][j], accNH[ct], 0, 0, 0);
      }
    }

    // ---- per-wave partial slots (parity pcur): coalesced, conflict-free ----
    {
      float* pw = pcur + w*2048 + lane*4;
      #pragma unroll
      for (int ct = 0; ct < 2; ++ct) {
        *(f32x4*)(pw +    0 + ct*256) = accR[ct];
        *(f32x4*)(pw +  512 + ct*256) = accZ[ct];
        *(f32x4*)(pw + 1024 + ct*256) = accNX[ct];
        *(f32x4*)(pw + 1536 + ct*256) = accNH[ct];
      }
    }
    __syncthreads();   // S3: the ONLY per-step barrier

    // ---- reduce over 8 wave-slots (contiguous reads) + gates + stores ----
    {
      float pr = 0.f, pz = 0.f, pnx = 0.f, pnh = 0.f;
      #pragma unroll
      for (int ww = 0; ww < 8; ++ww) {
        const float* pb = pcur + ww*2048;
        pr  += pb[tid];
        pz  += pb[512  + tid];
        pnx += pb[1024 + tid];
        pnh += pb[1536 + tid];
      }

      float r = 1.f/(1.f + __expf(-(pr + biasR[rcol])));
      float z = 1.f/(1.f + __expf(-(pz + biasZ[rcol])));
      float nin = pnx + biasNX[rcol] + r*(pnh + biasNH[rcol]);
      float e2 = __expf(2.f*nin);
      float n = 1.f - 2.f/(e2 + 1.f);             // tanh
      float hn = (1.f - z)*n + z*hold;
      hold = hn;

      const unsigned b = g*MB + rrow, hcol = colbase + rcol;
      unsigned short u = (unsigned short)((f2bf(hn) & ~1u) | tagd);
      __hip_atomic_store(hd + (size_t)b*Hq + hcol, u,
                         __ATOMIC_RELAXED, __HIP_MEMORY_SCOPE_AGENT);
      out[(size_t)b*SHq + (size_t)(t+1)*Hq + hcol] = hn;
      if (t == TSTEPS-1)
        out[(size_t)Bq*SHq + (size_t)b*Hq + hcol] = hn;
    }
    // no S4: next step's P writes go to parity (t+1)&1; this parity's reads
    // complete before S3(t+1), and t+2 writes to it happen after S3(t+1).
  }
}

extern "C" void kernel_launch(void* const* d_in, const int* in_sizes, int n_in,
                              void* d_out, int out_size, void* d_ws, size_t ws_size,
                              hipStream_t stream) {
  const float* x     = (const float*)d_in[0];
  const float* h0    = (const float*)d_in[1];
  const float* w_ir  = (const float*)d_in[2];
  const float* w_iz  = (const float*)d_in[3];
  const float* w_in_ = (const float*)d_in[4];
  const float* b_ir  = (const float*)d_in[5];
  const float* b_iz  = (const float*)d_in[6];
  const float* b_in_ = (const float*)d_in[7];
  const float* w_hr  = (const float*)d_in[8];
  const float* w_hz  = (const float*)d_in[9];
  const float* w_hn  = (const float*)d_in[10];
  const float* b_hr  = (const float*)d_in[11];
  const float* b_hz  = (const float*)d_in[12];
  const float* b_hn  = (const float*)d_in[13];
  float* out = (float*)d_out;

  // Precondition both tagged h ping-pong buffers to ALL-STALE (0xFFFF: tag 1,
  // bf16 NaN) -- erases replay leftovers and the harness's 0xAA ws-poison.
  hipMemsetAsync(d_ws, 0xFF, (size_t)2 * Bq * Hq * sizeof(unsigned short), stream);

  void* args[] = { (void*)&x, (void*)&h0, (void*)&w_ir, (void*)&w_iz, (void*)&w_in_,
                   (void*)&b_ir, (void*)&b_iz, (void*)&b_in_, (void*)&w_hr, (void*)&w_hz,
                   (void*)&w_hn, (void*)&b_hr, (void*)&b_hz, (void*)&b_hn,
                   (void*)&out, (void*)&d_ws };
  hipLaunchCooperativeKernel((void*)gru_kernel, dim3(128), dim3(512), args, 0, stream);
}

// Round 14
// 1263.099 us; speedup vs baseline: 1.4982x; 1.3288x over previous
//
#include <hip/hip_runtime.h>
#include <hip/hip_bf16.h>

typedef __bf16 bf16x8 __attribute__((ext_vector_type(8)));
typedef float  f32x4  __attribute__((ext_vector_type(4)));
typedef unsigned long long ull;

#define Bq 64
#define Sq 512
#define Iq 512
#define Hq 1024
#define TSTEPS 511
#define MB 16          // batches per group (4 groups x 32 blocks = 128 CUs)
#define NCOLS 32       // h-columns per block
#define SHq (Sq*Hq)
#define TAGM 0x0001000100010001ull

__device__ inline unsigned short f2bf(float f){ return __builtin_bit_cast(unsigned short, (__bf16)f); }

// swizzled LDS byte addresses (break the 2048B/1024B row-stride bank conflict)
__device__ inline unsigned ah_addr(unsigned row, unsigned k){ return ((row<<11) + (k<<1)) ^ ((row&7)<<4); }
__device__ inline unsigned ax_addr(unsigned row, unsigned k){ return ((row<<10) + (k<<1)) ^ ((row&7)<<4); }

__device__ inline bf16x8 load_wfrag(const float* p){
  float4 a = *(const float4*)p;
  float4 b = *(const float4*)(p+4);
  bf16x8 w;
  w[0]=(__bf16)a.x; w[1]=(__bf16)a.y; w[2]=(__bf16)a.z; w[3]=(__bf16)a.w;
  w[4]=(__bf16)b.x; w[5]=(__bf16)b.y; w[6]=(__bf16)b.z; w[7]=(__bf16)b.w;
  return w;
}

// anti-remat tie (keeps weight frags resident in the unified VGPR/AGPR file)
#define KEEP(v_) asm volatile("" : "+v"(v_))

// Tag protocol (r5): h^s lives in buffer s&1; every stored bf16's LSB =
// (s>>1)&1. kernel_launch memsets both buffers to 0xFF (stale for t=0/1;
// erases replay leftovers and the 0xAA ws-poison).
// Structure = r11 (best measured: 1295us) with ONE isolated delta:
// gate-interleaved P slots ([elem][4 gates] = 16B) so the reduce does
// 8x ds_read_b128 instead of 32x ds_read_b32. Everything else verbatim:
// 4 groups x 32 blocks, 8-way K-split, fully wave-private staging (no
// barrier before MFMA), staged-LDS h path, S3+S4, no fp LDS atomics.
__global__ __launch_bounds__(512, 1) void gru_kernel(
    const float* __restrict__ x, const float* __restrict__ h0,
    const float* __restrict__ w_ir, const float* __restrict__ w_iz, const float* __restrict__ w_in_,
    const float* __restrict__ b_ir, const float* __restrict__ b_iz, const float* __restrict__ b_in_,
    const float* __restrict__ w_hr, const float* __restrict__ w_hz, const float* __restrict__ w_hn,
    const float* __restrict__ b_hr, const float* __restrict__ b_hz, const float* __restrict__ b_hn,
    float* __restrict__ out, void* ws)
{
  __shared__ unsigned short Ah[MB*Hq];   // 32 KB, swizzled, wave-sliced by k-stripe
  __shared__ unsigned short Ax[MB*Iq];   // 16 KB, swizzled, wave-sliced by k-stripe
  __shared__ float P[8*2048];            // 64 KB per-wave slots [elem 512][gate 4]
  __shared__ float biasR[NCOLS], biasZ[NCOLS], biasNX[NCOLS], biasNH[NCOLS];

  const unsigned tid    = threadIdx.x;
  const unsigned bid    = blockIdx.x;
  const unsigned g      = bid & 3;        // batch group: 32 blocks
  const unsigned colbase= (bid >> 2) * NCOLS;
  const unsigned lane   = tid & 63;
  const unsigned w      = tid >> 6;       // wave = K-eighth
  const unsigned l15    = lane & 15;
  const unsigned l4     = lane >> 4;

  unsigned short* hb0 = (unsigned short*)ws;          // ping-pong tagged h buffers
  unsigned short* hb1 = hb0 + Bq*Hq;

  if (tid < NCOLS) {
    unsigned c = colbase + tid;
    biasR[tid]  = b_ir[c] + b_hr[c];
    biasZ[tid]  = b_iz[c] + b_hz[c];
    biasNX[tid] = b_in_[c];
    biasNH[tid] = b_hn[c];
  }

  // ---- reduce role: ownership derived from the gate-interleaved P layout
  //      (elem e = tid -> ct=tid>>8, row=(tid>>4)&15, colw=tid&15); reads are
  //      one b128 per wave-slot. hold lives in a REGISTER.
  const unsigned rrow = (tid >> 4) & 15;                // 0..15
  const unsigned rcol = (tid >> 8)*16 + (tid & 15);     // 0..31
  float hold;
  {
    unsigned b = g*MB + rrow, hcol = colbase + rcol;
    hold = h0[(size_t)b*Hq + hcol];
    out[(size_t)b*SHq + hcol] = hold;
    unsigned short u = (unsigned short)(f2bf(hold) & ~1u);   // tag 0
    __hip_atomic_store(hb0 + (size_t)b*Hq + hcol, u,
                       __ATOMIC_RELAXED, __HIP_MEMORY_SCOPE_AGENT);
  }

  // ---- stationary weights: 36 frags/wave (144 regs, VGPR/AGPR unified) ----
  // B-frag (16x16x32): col = lane&15, k = (lane>>4)*8 + [0..7]
  bf16x8 wRX[2][2], wZX[2][2], wNX[2][2];   // [ct][j], x ksteps w*2+j
  bf16x8 wRH[2][4], wZH[2][4], wNH[2][4];   // [ct][j], h ksteps w*4+j
  #pragma unroll
  for (int ct = 0; ct < 2; ++ct) {
    const unsigned hcf = colbase + ct*16 + l15;
    #pragma unroll
    for (int j = 0; j < 2; ++j) {
      unsigned off = (w*2 + j)*32 + l4*8;
      wRX[ct][j] = load_wfrag(w_ir  + (size_t)hcf*Iq + off);
      wZX[ct][j] = load_wfrag(w_iz  + (size_t)hcf*Iq + off);
      wNX[ct][j] = load_wfrag(w_in_ + (size_t)hcf*Iq + off);
      KEEP(wRX[ct][j]); KEEP(wZX[ct][j]); KEEP(wNX[ct][j]);
    }
    #pragma unroll
    for (int j = 0; j < 4; ++j) {
      unsigned off = (w*4 + j)*32 + l4*8;
      wRH[ct][j] = load_wfrag(w_hr + (size_t)hcf*Hq + off);
      wZH[ct][j] = load_wfrag(w_hz + (size_t)hcf*Hq + off);
      wNH[ct][j] = load_wfrag(w_hn + (size_t)hcf*Hq + off);
      KEEP(wRH[ct][j]); KEEP(wZH[ct][j]); KEEP(wNH[ct][j]);
    }
  }

  // ---- staging roles ----
  const unsigned xcr = lane >> 4, xc16 = lane & 15;  // x: coalesced 256B row-chunks
  const unsigned hch = lane & 31, hrb = lane >> 5;   // h: rows hrb+2i (i<8), ull @ w*128+hch*4

  // ---- x prefetch for t=0 (slab 1): wave-private k-stripe, coalesced ----
  float4 xpf[4];
  #pragma unroll
  for (int i = 0; i < 4; ++i)
    xpf[i] = *(const float4*)(x + ((size_t)(g*MB + xcr + 4*i)*Sq + 1)*Iq + w*64 + xc16*4);

  for (int t = 0; t < TSTEPS; ++t) {
    const unsigned short* hs = (t & 1) ? hb1 : hb0;
    unsigned short*       hd = (t & 1) ? hb0 : hb1;
    const ull want = ((t >> 1) & 1) ? TAGM : 0ull;
    const unsigned tagd = ((t + 1) >> 1) & 1;

    // ---- stage own x stripe from prefetched regs (wave-private, no barrier) ----
    #pragma unroll
    for (int i = 0; i < 4; ++i) {
      float4 v = xpf[i];
      ull pv = (ull)f2bf(v.x) | ((ull)f2bf(v.y) << 16)
             | ((ull)f2bf(v.z) << 32) | ((ull)f2bf(v.w) << 48);
      *(ull*)((char*)Ax + ax_addr(xcr + 4*i, w*64 + xc16*4)) = pv;
    }

    // ---- poll own h stripe (16 rows x 128 cols): 8x8B, retry stale w/ backoff ----
    ull hv[8];
    const unsigned short* hsg = hs + (size_t)(g*MB)*Hq + w*128;
    #pragma unroll
    for (int i = 0; i < 8; ++i)
      hv[i] = __hip_atomic_load((const ull*)(hsg + (size_t)(hrb + 2*i)*Hq) + hch,
                                __ATOMIC_RELAXED, __HIP_MEMORY_SCOPE_AGENT);
    for (;;) {
      unsigned stale = 0;
      #pragma unroll
      for (int i = 0; i < 8; ++i)
        if ((hv[i] & TAGM) != want) stale |= 1u << i;
      if (!stale) break;
      __builtin_amdgcn_s_sleep(1);
      #pragma unroll
      for (int i = 0; i < 8; ++i)
        if (stale & (1u << i))
          hv[i] = __hip_atomic_load((const ull*)(hsg + (size_t)(hrb + 2*i)*Hq) + hch,
                                    __ATOMIC_RELAXED, __HIP_MEMORY_SCOPE_AGENT);
    }

    // ---- x prefetch for t+2 (coalesced; hidden under MFMA+reduce) ----
    {
      int tt = (t + 2 <= Sq - 1) ? (t + 2) : (Sq - 1);
      #pragma unroll
      for (int i = 0; i < 4; ++i)
        xpf[i] = *(const float4*)(x + ((size_t)(g*MB + xcr + 4*i)*Sq + (size_t)tt)*Iq + w*64 + xc16*4);
    }

    // ---- h -> own Ah stripe (wave-private; no barrier before MFMA) ----
    #pragma unroll
    for (int i = 0; i < 8; ++i)
      *(ull*)((char*)Ah + ah_addr(hrb + 2*i, w*128 + hch*4)) = hv[i];

    // ---- MFMAs: 36/wave (2 col-tiles x {x:2 + h:4 ksteps} x 3 gates) ----
    f32x4 accR[2]={{0,0,0,0},{0,0,0,0}}, accZ[2]={{0,0,0,0},{0,0,0,0}};
    f32x4 accNX[2]={{0,0,0,0},{0,0,0,0}}, accNH[2]={{0,0,0,0},{0,0,0,0}};
    #pragma unroll
    for (int j = 0; j < 2; ++j) {
      bf16x8 a = *(const bf16x8*)((char*)Ax + ax_addr(l15, (w*2 + j)*32 + l4*8));
      #pragma unroll
      for (int ct = 0; ct < 2; ++ct) {
        accR[ct]  = __builtin_amdgcn_mfma_f32_16x16x32_bf16(a, wRX[ct][j], accR[ct], 0, 0, 0);
        accZ[ct]  = __builtin_amdgcn_mfma_f32_16x16x32_bf16(a, wZX[ct][j], accZ[ct], 0, 0, 0);
        accNX[ct] = __builtin_amdgcn_mfma_f32_16x16x32_bf16(a, wNX[ct][j], accNX[ct], 0, 0, 0);
      }
    }
    #pragma unroll
    for (int j = 0; j < 4; ++j) {
      bf16x8 a = *(const bf16x8*)((char*)Ah + ah_addr(l15, (w*4 + j)*32 + l4*8));
      #pragma unroll
      for (int ct = 0; ct < 2; ++ct) {
        accR[ct]  = __builtin_amdgcn_mfma_f32_16x16x32_bf16(a, wRH[ct][j], accR[ct], 0, 0, 0);
        accZ[ct]  = __builtin_amdgcn_mfma_f32_16x16x32_bf16(a, wZH[ct][j], accZ[ct], 0, 0, 0);
        accNH[ct] = __builtin_amdgcn_mfma_f32_16x16x32_bf16(a, wNH[ct][j], accNH[ct], 0, 0, 0);
      }
    }

    // ---- per-wave slots, gate-interleaved: elem e=(ct*256+(l4*4+i)*16+l15),
    //      one b128 = {R,Z,NX,NH} at float idx 4e (contiguous, conflict-free) ----
    {
      float* pw = P + w*2048;
      #pragma unroll
      for (int ct = 0; ct < 2; ++ct)
        #pragma unroll
        for (int i = 0; i < 4; ++i) {
          unsigned fi = (ct*256 + (l4*4 + i)*16 + l15) * 4;
          f32x4 v = { accR[ct][i], accZ[ct][i], accNX[ct][i], accNH[ct][i] };
          *(f32x4*)(pw + fi) = v;
        }
    }
    __syncthreads();   // S3: partials visible

    // ---- reduce over 8 wave-slots: ONE b128 per slot (contiguous) ----
    {
      float pr = 0.f, pz = 0.f, pnx = 0.f, pnh = 0.f;
      #pragma unroll
      for (int ww = 0; ww < 8; ++ww) {
        f32x4 v = *(const f32x4*)(P + ww*2048 + tid*4);
        pr += v[0]; pz += v[1]; pnx += v[2]; pnh += v[3];
      }

      float r = 1.f/(1.f + __expf(-(pr + biasR[rcol])));
      float z = 1.f/(1.f + __expf(-(pz + biasZ[rcol])));
      float nin = pnx + biasNX[rcol] + r*(pnh + biasNH[rcol]);
      float e2 = __expf(2.f*nin);
      float n = 1.f - 2.f/(e2 + 1.f);             // tanh
      float hn = (1.f - z)*n + z*hold;
      hold = hn;

      const unsigned b = g*MB + rrow, hcol = colbase + rcol;
      unsigned short u = (unsigned short)((f2bf(hn) & ~1u) | tagd);
      __hip_atomic_store(hd + (size_t)b*Hq + hcol, u,
                         __ATOMIC_RELAXED, __HIP_MEMORY_SCOPE_AGENT);
      out[(size_t)b*SHq + (size_t)(t+1)*Hq + hcol] = hn;
      if (t == TSTEPS-1)
        out[(size_t)Bq*SHq + (size_t)b*Hq + hcol] = hn;
    }
    __syncthreads();   // S4: P reads done before next step's P writes
  }
}

extern "C" void kernel_launch(void* const* d_in, const int* in_sizes, int n_in,
                              void* d_out, int out_size, void* d_ws, size_t ws_size,
                              hipStream_t stream) {
  const float* x     = (const float*)d_in[0];
  const float* h0    = (const float*)d_in[1];
  const float* w_ir  = (const float*)d_in[2];
  const float* w_iz  = (const float*)d_in[3];
  const float* w_in_ = (const float*)d_in[4];
  const float* b_ir  = (const float*)d_in[5];
  const float* b_iz  = (const float*)d_in[6];
  const float* b_in_ = (const float*)d_in[7];
  const float* w_hr  = (const float*)d_in[8];
  const float* w_hz  = (const float*)d_in[9];
  const float* w_hn  = (const float*)d_in[10];
  const float* b_hr  = (const float*)d_in[11];
  const float* b_hz  = (const float*)d_in[12];
  const float* b_hn  = (const float*)d_in[13];
  float* out = (float*)d_out;

  // Precondition both tagged h ping-pong buffers to ALL-STALE (0xFFFF: tag 1,
  // bf16 NaN) -- erases replay leftovers and the harness's 0xAA ws-poison.
  hipMemsetAsync(d_ws, 0xFF, (size_t)2 * Bq * Hq * sizeof(unsigned short), stream);

  void* args[] = { (void*)&x, (void*)&h0, (void*)&w_ir, (void*)&w_iz, (void*)&w_in_,
                   (void*)&b_ir, (void*)&b_iz, (void*)&b_in_, (void*)&w_hr, (void*)&w_hz,
                   (void*)&w_hn, (void*)&b_hr, (void*)&b_hz, (void*)&b_hn,
                   (void*)&out, (void*)&d_ws };
  hipLaunchCooperativeKernel((void*)gru_kernel, dim3(128), dim3(512), args, 0, stream);
}

// Round 15
// 1230.878 us; speedup vs baseline: 1.5374x; 1.0262x over previous
//
#include <hip/hip_runtime.h>
#include <hip/hip_bf16.h>

typedef __bf16 bf16x8 __attribute__((ext_vector_type(8)));
typedef float  f32x4  __attribute__((ext_vector_type(4)));
typedef unsigned long long ull;

#define Bq 64
#define Sq 512
#define Iq 512
#define Hq 1024
#define TSTEPS 511
#define MB 16          // batches per group (4 groups x 32 blocks = 128 CUs)
#define NCOLS 32       // h-columns per block
#define SHq (Sq*Hq)
#define TAGM 0x0001000100010001ull

__device__ inline unsigned short f2bf(float f){ return __builtin_bit_cast(unsigned short, (__bf16)f); }

// swizzled LDS byte addresses (break the 2048B/1024B row-stride bank conflict)
__device__ inline unsigned ah_addr(unsigned row, unsigned k){ return ((row<<11) + (k<<1)) ^ ((row&7)<<4); }
__device__ inline unsigned ax_addr(unsigned row, unsigned k){ return ((row<<10) + (k<<1)) ^ ((row&7)<<4); }

__device__ inline bf16x8 load_wfrag(const float* p){
  float4 a = *(const float4*)p;
  float4 b = *(const float4*)(p+4);
  bf16x8 w;
  w[0]=(__bf16)a.x; w[1]=(__bf16)a.y; w[2]=(__bf16)a.z; w[3]=(__bf16)a.w;
  w[4]=(__bf16)b.x; w[5]=(__bf16)b.y; w[6]=(__bf16)b.z; w[7]=(__bf16)b.w;
  return w;
}

// anti-remat tie (keeps weight frags resident in the unified VGPR/AGPR file)
#define KEEP(v_) asm volatile("" : "+v"(v_))

// LDS-only block barrier: lgkmcnt(0) + raw s_barrier, NO vmcnt(0) drain.
// __syncthreads would stall on the in-flight x HBM prefetch (~900cy) at S3
// and on the just-issued h/out stores (~400cy) at S4 -- neither is needed:
// LDS ordering (P, bias) needs only lgkmcnt; h-store visibility is absorbed
// by the consumers' data poll (tag protocol verifies per-location); xpf
// consumption gets its own compiler vmcnt wait at next iter's staging.
__device__ inline void block_sync_lds(){
  asm volatile("" ::: "memory");
  asm volatile("s_waitcnt lgkmcnt(0)" ::: "memory");
  __builtin_amdgcn_s_barrier();
  asm volatile("" ::: "memory");
}

// Tag protocol (r5): h^s lives in buffer s&1; every stored bf16's LSB =
// (s>>1)&1. kernel_launch memsets both buffers to 0xFF (stale for t=0/1;
// erases replay leftovers and the 0xAA ws-poison).
// Structure = r14 (best measured: 1263us) with two isolated deltas:
//  (1) S3/S4 are lgkm-only raw barriers (no vmcnt drain -- see block_sync_lds);
//  (2) the 12 x-part MFMAs run between poll-issue and the spin (they touch
//      only Ax/lgkm, so they overlap the h poll loads' flight).
// Everything else verbatim: 4 groups x 32 blocks, 8-way K-split, wave-private
// staging, staged-LDS h path, gate-interleaved P, no fp LDS atomics.
__global__ __launch_bounds__(512, 1) void gru_kernel(
    const float* __restrict__ x, const float* __restrict__ h0,
    const float* __restrict__ w_ir, const float* __restrict__ w_iz, const float* __restrict__ w_in_,
    const float* __restrict__ b_ir, const float* __restrict__ b_iz, const float* __restrict__ b_in_,
    const float* __restrict__ w_hr, const float* __restrict__ w_hz, const float* __restrict__ w_hn,
    const float* __restrict__ b_hr, const float* __restrict__ b_hz, const float* __restrict__ b_hn,
    float* __restrict__ out, void* ws)
{
  __shared__ unsigned short Ah[MB*Hq];   // 32 KB, swizzled, wave-sliced by k-stripe
  __shared__ unsigned short Ax[MB*Iq];   // 16 KB, swizzled, wave-sliced by k-stripe
  __shared__ float P[8*2048];            // 64 KB per-wave slots [elem 512][gate 4]
  __shared__ float biasR[NCOLS], biasZ[NCOLS], biasNX[NCOLS], biasNH[NCOLS];

  const unsigned tid    = threadIdx.x;
  const unsigned bid    = blockIdx.x;
  const unsigned g      = bid & 3;        // batch group: 32 blocks
  const unsigned colbase= (bid >> 2) * NCOLS;
  const unsigned lane   = tid & 63;
  const unsigned w      = tid >> 6;       // wave = K-eighth
  const unsigned l15    = lane & 15;
  const unsigned l4     = lane >> 4;

  unsigned short* hb0 = (unsigned short*)ws;          // ping-pong tagged h buffers
  unsigned short* hb1 = hb0 + Bq*Hq;

  if (tid < NCOLS) {
    unsigned c = colbase + tid;
    biasR[tid]  = b_ir[c] + b_hr[c];
    biasZ[tid]  = b_iz[c] + b_hz[c];
    biasNX[tid] = b_in_[c];
    biasNH[tid] = b_hn[c];
  }

  // ---- reduce role: ownership from the gate-interleaved P layout; hold in REGISTER ----
  const unsigned rrow = (tid >> 4) & 15;                // 0..15
  const unsigned rcol = (tid >> 8)*16 + (tid & 15);     // 0..31
  float hold;
  {
    unsigned b = g*MB + rrow, hcol = colbase + rcol;
    hold = h0[(size_t)b*Hq + hcol];
    out[(size_t)b*SHq + hcol] = hold;
    unsigned short u = (unsigned short)(f2bf(hold) & ~1u);   // tag 0
    __hip_atomic_store(hb0 + (size_t)b*Hq + hcol, u,
                       __ATOMIC_RELAXED, __HIP_MEMORY_SCOPE_AGENT);
  }

  // ---- stationary weights: 36 frags/wave (144 regs, VGPR/AGPR unified) ----
  // B-frag (16x16x32): col = lane&15, k = (lane>>4)*8 + [0..7]
  bf16x8 wRX[2][2], wZX[2][2], wNX[2][2];   // [ct][j], x ksteps w*2+j
  bf16x8 wRH[2][4], wZH[2][4], wNH[2][4];   // [ct][j], h ksteps w*4+j
  #pragma unroll
  for (int ct = 0; ct < 2; ++ct) {
    const unsigned hcf = colbase + ct*16 + l15;
    #pragma unroll
    for (int j = 0; j < 2; ++j) {
      unsigned off = (w*2 + j)*32 + l4*8;
      wRX[ct][j] = load_wfrag(w_ir  + (size_t)hcf*Iq + off);
      wZX[ct][j] = load_wfrag(w_iz  + (size_t)hcf*Iq + off);
      wNX[ct][j] = load_wfrag(w_in_ + (size_t)hcf*Iq + off);
      KEEP(wRX[ct][j]); KEEP(wZX[ct][j]); KEEP(wNX[ct][j]);
    }
    #pragma unroll
    for (int j = 0; j < 4; ++j) {
      unsigned off = (w*4 + j)*32 + l4*8;
      wRH[ct][j] = load_wfrag(w_hr + (size_t)hcf*Hq + off);
      wZH[ct][j] = load_wfrag(w_hz + (size_t)hcf*Hq + off);
      wNH[ct][j] = load_wfrag(w_hn + (size_t)hcf*Hq + off);
      KEEP(wRH[ct][j]); KEEP(wZH[ct][j]); KEEP(wNH[ct][j]);
    }
  }

  // ---- staging roles ----
  const unsigned xcr = lane >> 4, xc16 = lane & 15;  // x: coalesced 256B row-chunks
  const unsigned hch = lane & 31, hrb = lane >> 5;   // h: rows hrb+2i (i<8), ull @ w*128+hch*4

  // ---- x prefetch for t=0 (slab 1): wave-private k-stripe, coalesced ----
  float4 xpf[4];
  #pragma unroll
  for (int i = 0; i < 4; ++i)
    xpf[i] = *(const float4*)(x + ((size_t)(g*MB + xcr + 4*i)*Sq + 1)*Iq + w*64 + xc16*4);

  for (int t = 0; t < TSTEPS; ++t) {
    const unsigned short* hs = (t & 1) ? hb1 : hb0;
    unsigned short*       hd = (t & 1) ? hb0 : hb1;
    const ull want = ((t >> 1) & 1) ? TAGM : 0ull;
    const unsigned tagd = ((t + 1) >> 1) & 1;

    // ---- stage own x stripe from prefetched regs (wave-private, no barrier) ----
    #pragma unroll
    for (int i = 0; i < 4; ++i) {
      float4 v = xpf[i];
      ull pv = (ull)f2bf(v.x) | ((ull)f2bf(v.y) << 16)
             | ((ull)f2bf(v.z) << 32) | ((ull)f2bf(v.w) << 48);
      *(ull*)((char*)Ax + ax_addr(xcr + 4*i, w*64 + xc16*4)) = pv;
    }

    // ---- issue poll loads for own h stripe (16 rows x 128 cols): 8x8B ----
    ull hv[8];
    const unsigned short* hsg = hs + (size_t)(g*MB)*Hq + w*128;
    #pragma unroll
    for (int i = 0; i < 8; ++i)
      hv[i] = __hip_atomic_load((const ull*)(hsg + (size_t)(hrb + 2*i)*Hq) + hch,
                                __ATOMIC_RELAXED, __HIP_MEMORY_SCOPE_AGENT);

    // ---- x-part MFMAs (12): Ax/lgkm only -> overlap the h poll flight ----
    f32x4 accR[2]={{0,0,0,0},{0,0,0,0}}, accZ[2]={{0,0,0,0},{0,0,0,0}};
    f32x4 accNX[2]={{0,0,0,0},{0,0,0,0}}, accNH[2]={{0,0,0,0},{0,0,0,0}};
    #pragma unroll
    for (int j = 0; j < 2; ++j) {
      bf16x8 a = *(const bf16x8*)((char*)Ax + ax_addr(l15, (w*2 + j)*32 + l4*8));
      #pragma unroll
      for (int ct = 0; ct < 2; ++ct) {
        accR[ct]  = __builtin_amdgcn_mfma_f32_16x16x32_bf16(a, wRX[ct][j], accR[ct], 0, 0, 0);
        accZ[ct]  = __builtin_amdgcn_mfma_f32_16x16x32_bf16(a, wZX[ct][j], accZ[ct], 0, 0, 0);
        accNX[ct] = __builtin_amdgcn_mfma_f32_16x16x32_bf16(a, wNX[ct][j], accNX[ct], 0, 0, 0);
      }
    }

    // ---- spin: retry only stale halves, with backoff ----
    for (;;) {
      unsigned stale = 0;
      #pragma unroll
      for (int i = 0; i < 8; ++i)
        if ((hv[i] & TAGM) != want) stale |= 1u << i;
      if (!stale) break;
      __builtin_amdgcn_s_sleep(1);
      #pragma unroll
      for (int i = 0; i < 8; ++i)
        if (stale & (1u << i))
          hv[i] = __hip_atomic_load((const ull*)(hsg + (size_t)(hrb + 2*i)*Hq) + hch,
                                    __ATOMIC_RELAXED, __HIP_MEMORY_SCOPE_AGENT);
    }

    // ---- x prefetch for t+2 (off the poll path; drain deferred to next-iter use) ----
    {
      int tt = (t + 2 <= Sq - 1) ? (t + 2) : (Sq - 1);
      #pragma unroll
      for (int i = 0; i < 4; ++i)
        xpf[i] = *(const float4*)(x + ((size_t)(g*MB + xcr + 4*i)*Sq + (size_t)tt)*Iq + w*64 + xc16*4);
    }

    // ---- h -> own Ah stripe (wave-private; no barrier before MFMA) ----
    #pragma unroll
    for (int i = 0; i < 8; ++i)
      *(ull*)((char*)Ah + ah_addr(hrb + 2*i, w*128 + hch*4)) = hv[i];

    // ---- h-part MFMAs (24) ----
    #pragma unroll
    for (int j = 0; j < 4; ++j) {
      bf16x8 a = *(const bf16x8*)((char*)Ah + ah_addr(l15, (w*4 + j)*32 + l4*8));
      #pragma unroll
      for (int ct = 0; ct < 2; ++ct) {
        accR[ct]  = __builtin_amdgcn_mfma_f32_16x16x32_bf16(a, wRH[ct][j], accR[ct], 0, 0, 0);
        accZ[ct]  = __builtin_amdgcn_mfma_f32_16x16x32_bf16(a, wZH[ct][j], accZ[ct], 0, 0, 0);
        accNH[ct] = __builtin_amdgcn_mfma_f32_16x16x32_bf16(a, wNH[ct][j], accNH[ct], 0, 0, 0);
      }
    }

    // ---- per-wave slots, gate-interleaved: one b128 = {R,Z,NX,NH} per elem ----
    {
      float* pw = P + w*2048;
      #pragma unroll
      for (int ct = 0; ct < 2; ++ct)
        #pragma unroll
        for (int i = 0; i < 4; ++i) {
          unsigned fi = (ct*256 + (l4*4 + i)*16 + l15) * 4;
          f32x4 v = { accR[ct][i], accZ[ct][i], accNX[ct][i], accNH[ct][i] };
          *(f32x4*)(pw + fi) = v;
        }
    }
    block_sync_lds();   // S3: partials visible (lgkm only, no vmem drain)

    // ---- reduce over 8 wave-slots: ONE b128 per slot (contiguous) ----
    {
      float pr = 0.f, pz = 0.f, pnx = 0.f, pnh = 0.f;
      #pragma unroll
      for (int ww = 0; ww < 8; ++ww) {
        f32x4 v = *(const f32x4*)(P + ww*2048 + tid*4);
        pr += v[0]; pz += v[1]; pnx += v[2]; pnh += v[3];
      }

      float r = 1.f/(1.f + __expf(-(pr + biasR[rcol])));
      float z = 1.f/(1.f + __expf(-(pz + biasZ[rcol])));
      float nin = pnx + biasNX[rcol] + r*(pnh + biasNH[rcol]);
      float e2 = __expf(2.f*nin);
      float n = 1.f - 2.f/(e2 + 1.f);             // tanh
      float hn = (1.f - z)*n + z*hold;
      hold = hn;

      const unsigned b = g*MB + rrow, hcol = colbase + rcol;
      unsigned short u = (unsigned short)((f2bf(hn) & ~1u) | tagd);
      __hip_atomic_store(hd + (size_t)b*Hq + hcol, u,
                         __ATOMIC_RELAXED, __HIP_MEMORY_SCOPE_AGENT);
      out[(size_t)b*SHq + (size_t)(t+1)*Hq + hcol] = hn;
      if (t == TSTEPS-1)
        out[(size_t)Bq*SHq + (size_t)b*Hq + hcol] = hn;
    }
    block_sync_lds();   // S4: P reads done before next step's P writes (lgkm only)
  }
}

extern "C" void kernel_launch(void* const* d_in, const int* in_sizes, int n_in,
                              void* d_out, int out_size, void* d_ws, size_t ws_size,
                              hipStream_t stream) {
  const float* x     = (const float*)d_in[0];
  const float* h0    = (const float*)d_in[1];
  const float* w_ir  = (const float*)d_in[2];
  const float* w_iz  = (const float*)d_in[3];
  const float* w_in_ = (const float*)d_in[4];
  const float* b_ir  = (const float*)d_in[5];
  const float* b_iz  = (const float*)d_in[6];
  const float* b_in_ = (const float*)d_in[7];
  const float* w_hr  = (const float*)d_in[8];
  const float* w_hz  = (const float*)d_in[9];
  const float* w_hn  = (const float*)d_in[10];
  const float* b_hr  = (const float*)d_in[11];
  const float* b_hz  = (const float*)d_in[12];
  const float* b_hn  = (const float*)d_in[13];
  float* out = (float*)d_out;

  // Precondition both tagged h ping-pong buffers to ALL-STALE (0xFFFF: tag 1,
  // bf16 NaN) -- erases replay leftovers and the harness's 0xAA ws-poison.
  hipMemsetAsync(d_ws, 0xFF, (size_t)2 * Bq * Hq * sizeof(unsigned short), stream);

  void* args[] = { (void*)&x, (void*)&h0, (void*)&w_ir, (void*)&w_iz, (void*)&w_in_,
                   (void*)&b_ir, (void*)&b_iz, (void*)&b_in_, (void*)&w_hr, (void*)&w_hz,
                   (void*)&w_hn, (void*)&b_hr, (void*)&b_hz, (void*)&b_hn,
                   (void*)&out, (void*)&d_ws };
  hipLaunchCooperativeKernel((void*)gru_kernel, dim3(128), dim3(512), args, 0, stream);
}